// Round 14
// baseline (1962.460 us; speedup 1.0000x reference)
//
#include <hip/hip_runtime.h>
#include <stdint.h>

typedef unsigned short u16;
typedef __bf16 bf16x8 __attribute__((ext_vector_type(8)));
typedef float f32x4 __attribute__((ext_vector_type(4)));

#define DEV static __device__ __forceinline__

DEV u16 f2bu(float f) {
    union { float f; unsigned u; } v; v.f = f;
    unsigned r = v.u + 0x7FFFu + ((v.u >> 16) & 1u);
    return (u16)(r >> 16);
}
DEV float b2f(u16 b) {
    union { unsigned u; float f; } v; v.u = ((unsigned)b) << 16;
    return v.f;
}
DEV float fast_tanh(float x) {
    float e = __expf(2.f * x);
    return 1.f - __fdividef(2.f, e + 1.f);
}
DEV float fast_sig(float x) {
    return __fdividef(1.f, 1.f + __expf(-x));
}
DEV void gload_lds(const u16* g, u16* l) {
    __builtin_amdgcn_global_load_lds((const __attribute__((address_space(1))) void*)g,
                                     (__attribute__((address_space(3))) void*)l, 16, 0, 0);
}

// ---------------------------------------------------------------------------
// Generic 128x128 MFMA GEMM (prologue GEMMs), BK=32, 4 waves (2x2).
// ---------------------------------------------------------------------------
template<bool A_F32, bool B_F32, bool B_KXN, bool OUT_BF16, bool BIAS>
__global__ __launch_bounds__(256) void gemm128(
    const void* __restrict__ Ap, int lda,
    const void* __restrict__ Bp, int ldb,
    void* __restrict__ Cp, int ldc,
    const float* __restrict__ bias, int K)
{
    __shared__ u16 As[128 * 40];
    __shared__ u16 Bs[128 * 40];
    const int tid = threadIdx.x;
    const int lane = tid & 63, wave = tid >> 6;
    const int wr = wave >> 1, wc = wave & 1;
    const int m0 = blockIdx.y * 128, n0 = blockIdx.x * 128;

    f32x4 acc[4][4];
#pragma unroll
    for (int m = 0; m < 4; ++m)
#pragma unroll
        for (int n = 0; n < 4; ++n)
            acc[m][n] = (f32x4){0.f, 0.f, 0.f, 0.f};

    for (int k0 = 0; k0 < K; k0 += 32) {
        __syncthreads();
        if (A_F32) {
            const float* A = (const float*)Ap;
#pragma unroll
            for (int i = 0; i < 4; ++i) {
                int c = tid + i * 256;
                int row = c >> 3, kc = (c & 7) * 4;
                float4 v = *(const float4*)&A[(size_t)(m0 + row) * lda + k0 + kc];
                ushort4 o; o.x = f2bu(v.x); o.y = f2bu(v.y); o.z = f2bu(v.z); o.w = f2bu(v.w);
                *(ushort4*)&As[row * 40 + kc] = o;
            }
        } else {
            const u16* A = (const u16*)Ap;
#pragma unroll
            for (int i = 0; i < 2; ++i) {
                int c = tid + i * 256;
                int row = c >> 2, kc = (c & 3) * 8;
                *(int4*)&As[row * 40 + kc] = *(const int4*)&A[(size_t)(m0 + row) * lda + k0 + kc];
            }
        }
        if (B_KXN) {
            const float* B = (const float*)Bp;
#pragma unroll
            for (int i = 0; i < 4; ++i) {
                int c = tid + i * 256;
                int kk = c >> 5, nc = (c & 31) * 4;
                float4 v = *(const float4*)&B[(size_t)(k0 + kk) * ldb + n0 + nc];
                Bs[(nc + 0) * 40 + kk] = f2bu(v.x);
                Bs[(nc + 1) * 40 + kk] = f2bu(v.y);
                Bs[(nc + 2) * 40 + kk] = f2bu(v.z);
                Bs[(nc + 3) * 40 + kk] = f2bu(v.w);
            }
        } else if (B_F32) {
            const float* B = (const float*)Bp;
#pragma unroll
            for (int i = 0; i < 4; ++i) {
                int c = tid + i * 256;
                int row = c >> 3, kc = (c & 7) * 4;
                float4 v = *(const float4*)&B[(size_t)(n0 + row) * ldb + k0 + kc];
                ushort4 o; o.x = f2bu(v.x); o.y = f2bu(v.y); o.z = f2bu(v.z); o.w = f2bu(v.w);
                *(ushort4*)&Bs[row * 40 + kc] = o;
            }
        } else {
            const u16* B = (const u16*)Bp;
#pragma unroll
            for (int i = 0; i < 2; ++i) {
                int c = tid + i * 256;
                int row = c >> 2, kc = (c & 3) * 8;
                *(int4*)&Bs[row * 40 + kc] = *(const int4*)&B[(size_t)(n0 + row) * ldb + k0 + kc];
            }
        }
        __syncthreads();
        const int fr = lane & 15, kq = (lane >> 4) * 8;
        bf16x8 af[4], bq[4];
#pragma unroll
        for (int m = 0; m < 4; ++m)
            af[m] = *(const bf16x8*)&As[(wr * 64 + m * 16 + fr) * 40 + kq];
#pragma unroll
        for (int n = 0; n < 4; ++n)
            bq[n] = *(const bf16x8*)&Bs[(wc * 64 + n * 16 + fr) * 40 + kq];
#pragma unroll
        for (int m = 0; m < 4; ++m)
#pragma unroll
            for (int n = 0; n < 4; ++n)
                acc[m][n] = __builtin_amdgcn_mfma_f32_16x16x32_bf16(af[m], bq[n], acc[m][n], 0, 0, 0);
    }
    const int fr = lane & 15, rq = (lane >> 4) * 4;
#pragma unroll
    for (int m = 0; m < 4; ++m) {
#pragma unroll
        for (int n = 0; n < 4; ++n) {
            int col = n0 + wc * 64 + n * 16 + fr;
            float bv = BIAS ? bias[col] : 0.f;
#pragma unroll
            for (int r = 0; r < 4; ++r) {
                int row = m0 + wr * 64 + m * 16 + rq + r;
                float v = acc[m][n][r] + bv;
                if (OUT_BF16) ((u16*)Cp)[(size_t)row * ldc + col] = f2bu(v);
                else          ((float*)Cp)[(size_t)row * ldc + col] = v;
            }
        }
    }
}

// ---------------------------------------------------------------------------
// Head GEMM (R13-proven): 256x256, BK=64, 16 waves, counted vmcnt pipeline.
// ---------------------------------------------------------------------------
__global__ __launch_bounds__(1024) void gemm_head(const u16* __restrict__ A,
                                                  const u16* __restrict__ B,
                                                  float* __restrict__ C)
{
    __shared__ u16 As[2][256 * 64];
    __shared__ u16 Bs[2][256 * 64];
    const int tid = threadIdx.x, lane = tid & 63, wave = tid >> 6;  // 0..15
    const int wr = wave >> 2, wc = wave & 3;
    int bid = blockIdx.x;                       // 1000 = 8 * 125
    int nb = (bid & 7) * 125 + (bid >> 3);      // XCD-chunked
    const int m0 = (nb & 7) * 256;              // m fastest -> B-panel L2 reuse
    const int n0 = (nb >> 3) * 256;

    f32x4 acc[4][4];
#pragma unroll
    for (int m = 0; m < 4; ++m)
#pragma unroll
        for (int n = 0; n < 4; ++n)
            acc[m][n] = (f32x4){0.f, 0.f, 0.f, 0.f};

    const int srg = lane >> 3;
    const int sslot = lane & 7;
    const int ge = (sslot ^ srg) * 8;
    const int fr = lane & 15, kg = lane >> 4;

#define STAGE(bf, kt)                                                              \
    {                                                                              \
        const int k0s = (kt) * 64;                                                 \
        _Pragma("unroll")                                                          \
        for (int j = 0; j < 2; ++j) {                                              \
            const int g = wave * 2 + j;                                            \
            gload_lds(&A[(size_t)(m0 + g * 8 + srg) * 1024 + k0s + ge],            \
                      &As[bf][g * 8 * 64]);                                        \
            gload_lds(&B[(size_t)(n0 + g * 8 + srg) * 1024 + k0s + ge],            \
                      &Bs[bf][g * 8 * 64]);                                        \
        }                                                                          \
    }

    STAGE(0, 0);
    STAGE(1, 1);
    asm volatile("s_waitcnt vmcnt(4)" ::: "memory");
    __builtin_amdgcn_s_barrier();

    for (int kt = 0; kt < 16; ++kt) {
        const int cur = kt & 1;
#pragma unroll
        for (int kk = 0; kk < 2; ++kk) {
            const int sl = kk * 4 + kg;
            bf16x8 af[4], bq[4];
#pragma unroll
            for (int m = 0; m < 4; ++m) {
                const int row = wr * 64 + m * 16 + fr;
                af[m] = *(const bf16x8*)&As[cur][row * 64 + ((sl ^ (row & 7)) << 3)];
            }
#pragma unroll
            for (int n = 0; n < 4; ++n) {
                const int row = wc * 64 + n * 16 + fr;
                bq[n] = *(const bf16x8*)&Bs[cur][row * 64 + ((sl ^ (row & 7)) << 3)];
            }
#pragma unroll
            for (int m = 0; m < 4; ++m)
#pragma unroll
                for (int n = 0; n < 4; ++n)
                    acc[m][n] = __builtin_amdgcn_mfma_f32_16x16x32_bf16(af[m], bq[n], acc[m][n], 0, 0, 0);
        }
        __builtin_amdgcn_s_barrier();
        if (kt + 2 < 16) {
            STAGE(cur, kt + 2);
            asm volatile("s_waitcnt vmcnt(4)" ::: "memory");
        } else {
            asm volatile("s_waitcnt vmcnt(0)" ::: "memory");
        }
        __builtin_amdgcn_s_barrier();
    }
#undef STAGE
    const int rq = kg * 4;
#pragma unroll
    for (int m = 0; m < 4; ++m)
#pragma unroll
        for (int n = 0; n < 4; ++n) {
            int col = n0 + wc * 64 + n * 16 + fr;
#pragma unroll
            for (int r = 0; r < 4; ++r)
                C[(size_t)(m0 + wr * 64 + m * 16 + rq + r) * 32000 + col] = acc[m][n][r];
        }
}

// ---------------------------------------------------------------------------
// Merged prologue conversions (WhidT packed k-major).
// ---------------------------------------------------------------------------
__global__ __launch_bounds__(256) void prep_k(
    const float* __restrict__ img, const float* __restrict__ Whh,
    const float* __restrict__ Whid, const float* __restrict__ Whead,
    const int* __restrict__ tok, const float* __restrict__ embed,
    const float* __restrict__ bih, const float* __restrict__ bhh,
    u16* __restrict__ img_bf, u16* __restrict__ Whh_bf,
    u16* __restrict__ WhidT, u16* __restrict__ Whead_bf,
    u16* __restrict__ emb_bf, float* __restrict__ bsum)
{
    const int bid = blockIdx.x;
    if (bid < 25088) {                       // img cvt
        int i = bid * 256 + threadIdx.x;
        float4 v = ((const float4*)img)[i];
        ushort4 o; o.x = f2bu(v.x); o.y = f2bu(v.y); o.z = f2bu(v.z); o.w = f2bu(v.w);
        ((ushort4*)img_bf)[i] = o;
    } else if (bid < 29184) {                // Whh cvt
        int i = (bid - 25088) * 256 + threadIdx.x;
        float4 v = ((const float4*)Whh)[i];
        ushort4 o; o.x = f2bu(v.x); o.y = f2bu(v.y); o.z = f2bu(v.z); o.w = f2bu(v.w);
        ((ushort4*)Whh_bf)[i] = o;
    } else if (bid < 29440) {                // WhidT pack
        int i = (bid - 29184) * 256 + threadIdx.x;   // 65536
        int a = i >> 8, k4 = (i & 255) * 4;
        float4 v = *(const float4*)&Whid[(size_t)a * 1024 + k4];
        ushort4 o; o.x = f2bu(v.x); o.y = f2bu(v.y); o.z = f2bu(v.z); o.w = f2bu(v.w);
        *(ushort4*)&WhidT[(size_t)(k4 >> 3) * 2048 + a * 8 + (k4 & 7)] = o;
    } else if (bid < 61440) {                // Whead cvt
        int i = (bid - 29440) * 256 + threadIdx.x;
        float4 v = ((const float4*)Whead)[i];
        ushort4 o; o.x = f2bu(v.x); o.y = f2bu(v.y); o.z = f2bu(v.z); o.w = f2bu(v.w);
        ((ushort4*)Whead_bf)[i] = o;
    } else if (bid < 65536) {                // emb gather, rows [t][b]
        int id = (bid - 61440) * 256 + threadIdx.x;
        int row = id >> 9, e = id & 511;
        int t = row >> 6, b = row & 63;
        int tk = tok[b * 32 + t];
        emb_bf[(size_t)row * 512 + e] = f2bu(embed[(size_t)tk * 512 + e]);
    } else {                                 // bias sum
        int i = (bid - 65536) * 256 + threadIdx.x;
        bsum[i] = bih[i] + bhh[i];
    }
}

// Fragment-pack gates weights: Wpk[bid][i][lane][8], i = K-iter (0..95).
__global__ __launch_bounds__(256) void pack_w(const u16* __restrict__ Wic,
                                              const u16* __restrict__ Whh,
                                              u16* __restrict__ Wpk)
{
    const int bid = blockIdx.y;
    const int t2 = blockIdx.x * 256 + threadIdx.x;   // 6144 = 96*64
    const int i = t2 >> 6, lane = t2 & 63;
    const int fr = lane & 15, kq = (lane >> 4) * 8;
    const int grow = ((fr >> 2) << 10) + bid * 4 + (fr & 3);
    const int k0 = i * 32;
    int4 v;
    if (k0 < 2048) v = *(const int4*)&Wic[(size_t)grow * 2048 + k0 + kq];
    else           v = *(const int4*)&Whh[(size_t)grow * 1024 + (k0 - 2048) + kq];
    *(int4*)&Wpk[((size_t)bid * 6144 + t2) * 8] = v;
}

// mean over n of img_bf
__global__ __launch_bounds__(256) void mean_k(const u16* __restrict__ img_bf, float* __restrict__ gT)
{
    int id = blockIdx.x * 256 + threadIdx.x;   // 65536
    int b = id >> 10;
    int d = (id & 1023) * 2;
    const u16* base = img_bf + (size_t)b * 196 * 2048 + d;
    float s0 = 0.f, s1 = 0.f;
#pragma unroll 4
    for (int n = 0; n < 196; ++n) {
        ushort2 v = *(const ushort2*)(base + (size_t)n * 2048);
        s0 += b2f(v.x);
        s1 += b2f(v.y);
    }
    gT[(d + 0) * 64 + b] = s0 * (1.f / 196.f);
    gT[(d + 1) * 64 + b] = s1 * (1.f / 196.f);
}

__global__ __launch_bounds__(256) void h0c0(const float* __restrict__ gT,
                                            const float* __restrict__ Wh0, const float* __restrict__ bh0,
                                            const float* __restrict__ Wc0, const float* __restrict__ bc0,
                                            float* __restrict__ c, u16* __restrict__ h0)
{
    int id = blockIdx.x * 256 + threadIdx.x;
    int b = id & 63, n = id >> 6;
    const float4* Wh = (const float4*)&Wh0[(size_t)n * 2048];
    const float4* Wc = (const float4*)&Wc0[(size_t)n * 2048];
    float s0 = 0.f, s1 = 0.f;
#pragma unroll 4
    for (int k4 = 0; k4 < 512; ++k4) {
        float4 wh = Wh[k4], wc = Wc[k4];
        float g0 = gT[(k4 * 4 + 0) * 64 + b];
        float g1 = gT[(k4 * 4 + 1) * 64 + b];
        float g2 = gT[(k4 * 4 + 2) * 64 + b];
        float g3 = gT[(k4 * 4 + 3) * 64 + b];
        s0 += wh.x * g0 + wh.y * g1 + wh.z * g2 + wh.w * g3;
        s1 += wc.x * g0 + wc.y * g1 + wc.z * g2 + wc.w * g3;
    }
    c[b * 1024 + n] = fast_tanh(s1 + bc0[n]);
    h0[(size_t)b * 1024 + n] = f2bu(fast_tanh(s0 + bh0[n]));
}

// ---------------------------------------------------------------------------
// Per-step kernel 1: sm_k — ph + scores + softmax -> probs. grid 64 (per b),
// 1024 threads. WhidT read once per b (33 MB/step vs 131 in fused attn).
// ---------------------------------------------------------------------------
__global__ __launch_bounds__(1024) void sm_k(const u16* __restrict__ hb,      // [64][1024]
                                             const u16* __restrict__ WhidT,   // [128][256][8]
                                             const float* __restrict__ w_score,
                                             const u16* __restrict__ proj_bf, // [64*196][256]
                                             float* __restrict__ probs)       // [64][256]
{
    const int b = blockIdx.x;
    const int tid = threadIdx.x, lane = tid & 63, wave = tid >> 6;  // 0..15
    __shared__ float ph[256], ws[256], sc[256];
    __shared__ float hsh[1024];
    __shared__ float php[4][256];

    if (tid < 256) {
        ws[tid] = w_score[tid];
        sc[tid] = -1e30f;
    }
    hsh[tid] = b2f(hb[(size_t)b * 1024 + tid]);
    __syncthreads();

    // ph[a] = dot(h_b, Whid[a]) : thread (a = tid&255, ks = tid>>8)
    {
        const int a = tid & 255, ks = tid >> 8;
        float s = 0.f;
        const u16* wp = WhidT + a * 8;
#pragma unroll 8
        for (int j = 0; j < 32; ++j) {
            const int kb = ks * 32 + j;
            bf16x8 wv = *(const bf16x8*)(wp + (size_t)kb * 2048);
            const float* hk = &hsh[kb * 8];
#pragma unroll
            for (int i = 0; i < 8; ++i) s += hk[i] * (float)wv[i];
        }
        php[ks][a] = s;
    }
    __syncthreads();
    if (tid < 256) ph[tid] = php[0][tid] + php[1][tid] + php[2][tid] + php[3][tid];
    __syncthreads();

    // scores: wave w handles n = w, w+16, ...
    for (int n = wave; n < 196; n += 16) {
        const int a0 = lane * 4;
        ushort4 pv = *(const ushort4*)&proj_bf[((size_t)b * 196 + n) * 256 + a0];
        float s = ws[a0 + 0] * fast_tanh(b2f(pv.x) + ph[a0 + 0])
                + ws[a0 + 1] * fast_tanh(b2f(pv.y) + ph[a0 + 1])
                + ws[a0 + 2] * fast_tanh(b2f(pv.z) + ph[a0 + 2])
                + ws[a0 + 3] * fast_tanh(b2f(pv.w) + ph[a0 + 3]);
#pragma unroll
        for (int off = 32; off; off >>= 1) s += __shfl_xor(s, off, 64);
        if (lane == 0) sc[n] = s;
    }
    __syncthreads();

    // single-wave softmax over 256 (pad -1e30 -> 0), write probs
    if (wave == 0) {
        float v0 = sc[lane], v1 = sc[lane + 64], v2 = sc[lane + 128], v3 = sc[lane + 192];
        float mx = fmaxf(fmaxf(v0, v1), fmaxf(v2, v3));
#pragma unroll
        for (int off = 32; off; off >>= 1) mx = fmaxf(mx, __shfl_xor(mx, off, 64));
        float e0 = __expf(v0 - mx), e1 = __expf(v1 - mx);
        float e2 = __expf(v2 - mx), e3 = __expf(v3 - mx);
        float s = e0 + e1 + e2 + e3;
#pragma unroll
        for (int off = 32; off; off >>= 1) s += __shfl_xor(s, off, 64);
        const float inv = __fdividef(1.f, s);
        float* pb = probs + b * 256;
        pb[lane] = e0 * inv;
        pb[lane + 64] = e1 * inv;
        pb[lane + 128] = e2 * inv;
        pb[lane + 192] = e3 * inv;
    }
}

// ---------------------------------------------------------------------------
// Per-step kernel 2: ctx_k — weighted img sum. grid 256 = (b,q), 1024 threads.
// ---------------------------------------------------------------------------
__global__ __launch_bounds__(1024) void ctx_k(const float* __restrict__ probs, // [64][256]
                                              const u16* __restrict__ img_bf,  // [64][196][2048]
                                              u16* __restrict__ ctx_bf)        // [64][2048]
{
    const int b = blockIdx.x >> 2, q = blockIdx.x & 3;
    const int tid = threadIdx.x;
    __shared__ float sc[256];
    __shared__ float part[16][512];
    if (tid < 256) sc[tid] = probs[b * 256 + tid];
    __syncthreads();
    const int gid = tid >> 4, st = tid & 15;
    const int c0 = q * 512 + gid * 8;
    const u16* base = img_bf + ((size_t)b * 196) * 2048 + c0;
    float a[8];
#pragma unroll
    for (int i = 0; i < 8; ++i) a[i] = 0.f;
    for (int n = st; n < 196; n += 16) {
        bf16x8 v = *(const bf16x8*)(base + (size_t)n * 2048);
        float wgt = sc[n];
#pragma unroll
        for (int i = 0; i < 8; ++i) a[i] += wgt * (float)v[i];
    }
#pragma unroll
    for (int i = 0; i < 8; ++i) part[st][gid * 8 + i] = a[i];
    __syncthreads();
    if (tid < 512) {
        const int col = tid;
        float v = 0.f;
#pragma unroll
        for (int s16 = 0; s16 < 16; ++s16) v += part[s16][col];
        ctx_bf[(size_t)b * 2048 + q * 512 + col] = f2bu(v);
    }
}

// ---------------------------------------------------------------------------
// Per-step kernel 3 (R9-proven): gates MFMA + LSTM pointwise.
// grid 256 x 1024 threads, 16-wave K-split (192 each).
// ---------------------------------------------------------------------------
__global__ __launch_bounds__(1024) void gates_k(const u16* __restrict__ ctx_bf,  // [64][2048]
                                                const u16* __restrict__ hb,      // [64][1024]
                                                const u16* __restrict__ Wpk,     // [256][96][64][8]
                                                const float* __restrict__ xg,    // [32][64][4096]
                                                float* __restrict__ cbuf,        // [64][1024]
                                                u16* __restrict__ h_nxt,         // [64][1024]
                                                u16* __restrict__ h_all,         // [2048][1024]
                                                int t)
{
    const int tid = threadIdx.x, lane = tid & 63, wave = tid >> 6;  // 0..15
    const int fr = lane & 15, kq = (lane >> 4) * 8, rq = (lane >> 4) * 4;
    const int hc0 = blockIdx.x * 4;
    const u16* Wblk = Wpk + (size_t)blockIdx.x * 49152 + lane * 8;  // [96][64][8]
    __shared__ float red[16][64][16];

    f32x4 acc[4];
#pragma unroll
    for (int m = 0; m < 4; ++m) acc[m] = (f32x4){0.f, 0.f, 0.f, 0.f};

    const int kbeg = wave * 192, kend = kbeg + 192;
    const int cend = kend < 2048 ? kend : 2048;
#pragma unroll 2
    for (int k0 = kbeg; k0 < cend; k0 += 32) {
        bf16x8 bq = *(const bf16x8*)&Wblk[(size_t)(k0 >> 5) * 512];
#pragma unroll
        for (int m = 0; m < 4; ++m) {
            bf16x8 af = *(const bf16x8*)&ctx_bf[(size_t)(m * 16 + fr) * 2048 + k0 + kq];
            acc[m] = __builtin_amdgcn_mfma_f32_16x16x32_bf16(af, bq, acc[m], 0, 0, 0);
        }
    }
    const int hbeg = kbeg > 2048 ? kbeg - 2048 : 0;
    const int hend = kend > 2048 ? kend - 2048 : 0;
#pragma unroll 2
    for (int kh = hbeg; kh < hend; kh += 32) {
        bf16x8 bq = *(const bf16x8*)&Wblk[(size_t)((kh + 2048) >> 5) * 512];
#pragma unroll
        for (int m = 0; m < 4; ++m) {
            bf16x8 af = *(const bf16x8*)&hb[(size_t)(m * 16 + fr) * 1024 + kh + kq];
            acc[m] = __builtin_amdgcn_mfma_f32_16x16x32_bf16(af, bq, acc[m], 0, 0, 0);
        }
    }
#pragma unroll
    for (int m = 0; m < 4; ++m)
#pragma unroll
        for (int r = 0; r < 4; ++r)
            red[wave][m * 16 + rq + r][fr] = acc[m][r];
    __syncthreads();

    if (tid < 256) {
        const int bb = tid >> 2, j = tid & 3;
        const int col = hc0 + j;
        float G[4];
#pragma unroll
        for (int g = 0; g < 4; ++g) {
            const int f2 = g * 4 + j;
            float s = 0.f;
#pragma unroll
            for (int w16 = 0; w16 < 16; ++w16) s += red[w16][bb][f2];
            G[g] = s + xg[((size_t)t * 64 + bb) * 4096 + g * 1024 + col];
        }
        float ig = fast_sig(G[0]), fg = fast_sig(G[1]);
        float gv = fast_tanh(G[2]), og = fast_sig(G[3]);
        float cp = cbuf[bb * 1024 + col];
        float cn = fg * cp + ig * gv;
        cbuf[bb * 1024 + col] = cn;
        u16 hv = f2bu(og * fast_tanh(cn));
        h_nxt[(size_t)bb * 1024 + col] = hv;
        h_all[((size_t)bb * 32 + t) * 1024 + col] = hv;
    }
}

// ---------------------------------------------------------------------------
extern "C" void kernel_launch(void* const* d_in, const int* in_sizes, int n_in,
                              void* d_out, int out_size, void* d_ws, size_t ws_size,
                              hipStream_t stream)
{
    const float* img     = (const float*)d_in[0];
    const int*   tok     = (const int*)d_in[1];
    const float* embed   = (const float*)d_in[2];
    const float* W_head1 = (const float*)d_in[3];
    const float* W_ih    = (const float*)d_in[4];
    const float* W_hh    = (const float*)d_in[5];
    const float* b_ih    = (const float*)d_in[6];
    const float* b_hh    = (const float*)d_in[7];
    const float* W_head  = (const float*)d_in[8];
    const float* W_img   = (const float*)d_in[9];
    const float* W_hid   = (const float*)d_in[10];
    const float* w_score = (const float*)d_in[11];
    const float* W_h0    = (const float*)d_in[12];
    const float* b_h0    = (const float*)d_in[13];
    const float* W_c0    = (const float*)d_in[14];
    const float* b_c0    = (const float*)d_in[15];
    float* out = (float*)d_out;

    char* w = (char*)d_ws;
    size_t off = 0;
    auto alloc = [&](size_t bytes) { char* p = w + off; off += (bytes + 255) & ~(size_t)255; return p; };

    u16*   Wic      = (u16*)alloc(4096ULL * 2048 * 2);
    u16*   Whh_bf   = (u16*)alloc(4096ULL * 1024 * 2);
    u16*   Wpk      = (u16*)alloc(256ULL * 96 * 64 * 8 * 2);
    u16*   WhidT    = (u16*)alloc(256ULL * 1024 * 2);
    u16*   Whead_bf = (u16*)alloc(32000ULL * 1024 * 2);
    u16*   img_bf   = (u16*)alloc(64ULL * 196 * 2048 * 2);
    float* xg       = (float*)alloc(2048ULL * 4096 * 4);
    u16*   proj_bf  = (u16*)alloc(64ULL * 196 * 256 * 2);
    u16*   emb_bf   = (u16*)alloc(2048ULL * 512 * 2);
    u16*   xe       = (u16*)alloc(2048ULL * 512 * 2);
    float* gT       = (float*)alloc(2048ULL * 64 * 4);
    float* cbuf     = (float*)alloc(64ULL * 1024 * 4);
    u16*   hbuf     = (u16*)alloc(2ULL * 64 * 1024 * 2);
    u16*   ctx_bf   = (u16*)alloc(64ULL * 2048 * 2);
    u16*   h_all    = (u16*)alloc(2048ULL * 1024 * 2);
    float* probs    = (float*)alloc(64ULL * 256 * 4);
    float* bsum     = (float*)alloc(4096ULL * 4);
    (void)ws_size; (void)in_sizes; (void)n_in; (void)out_size;

    // ---- prologue (consolidated)
    prep_k<<<dim3(65552), dim3(256), 0, stream>>>(img, W_hh, W_hid, W_head, tok, embed,
                                                  b_ih, b_hh, img_bf, Whh_bf, WhidT,
                                                  Whead_bf, emb_bf, bsum);
    mean_k<<<dim3(256), dim3(256), 0, stream>>>(img_bf, gT);
    h0c0<<<dim3(256), dim3(256), 0, stream>>>(gT, W_h0, b_h0, W_c0, b_c0, cbuf, hbuf);

    // xe = emb @ Wa^T (Wa = W_head1[:, :512]); rows [t][b]
    gemm128<false, true, false, true, false><<<dim3(4, 16), dim3(256), 0, stream>>>(
        emb_bf, 512, W_head1, 2560, xe, 512, nullptr, 512);
    // xg = xe @ W_ih^T + (b_ih + b_hh); rows [t][b]
    gemm128<false, true, false, false, true><<<dim3(32, 16), dim3(256), 0, stream>>>(
        xe, 512, W_ih, 512, xg, 4096, bsum, 512);
    // Wic = W_ih @ W_head1[:, 512:]
    gemm128<true, true, true, true, false><<<dim3(16, 32), dim3(256), 0, stream>>>(
        W_ih, 512, W_head1 + 512, 2560, Wic, 2048, nullptr, 512);
    // proj_bf = img_bf @ W_img^T (bf16 out)
    gemm128<false, true, false, true, false><<<dim3(2, 98), dim3(256), 0, stream>>>(
        img_bf, 2048, W_img, 2048, proj_bf, 256, nullptr, 2048);
    // fragment-pack gates weights (needs Wic + Whh_bf)
    pack_w<<<dim3(24, 256), dim3(256), 0, stream>>>(Wic, Whh_bf, Wpk);

    // ---- recurrence: 3 kernels per step (sm / ctx / gates)
    for (int t = 0; t < 32; ++t) {
        u16* hb = hbuf + (size_t)(t & 1) * 65536;
        u16* hn = hbuf + (size_t)((t + 1) & 1) * 65536;
        sm_k<<<dim3(64), dim3(1024), 0, stream>>>(hb, WhidT, w_score, proj_bf, probs);
        ctx_k<<<dim3(256), dim3(1024), 0, stream>>>(probs, img_bf, ctx_bf);
        gates_k<<<dim3(256), dim3(1024), 0, stream>>>(ctx_bf, hb, Wpk, xg, cbuf, hn, h_all, t);
    }

    // ---- logits: out = h_all @ W_head^T (counted-vmcnt pipeline)
    gemm_head<<<dim3(1000), dim3(1024), 0, stream>>>(h_all, Whead_bf, out);
}

// Round 15
// 1937.584 us; speedup vs baseline: 1.0128x; 1.0128x over previous
//
#include <hip/hip_runtime.h>
#include <stdint.h>

typedef unsigned short u16;
typedef __bf16 bf16x8 __attribute__((ext_vector_type(8)));
typedef float f32x4 __attribute__((ext_vector_type(4)));

#define DEV static __device__ __forceinline__

DEV u16 f2bu(float f) {
    union { float f; unsigned u; } v; v.f = f;
    unsigned r = v.u + 0x7FFFu + ((v.u >> 16) & 1u);
    return (u16)(r >> 16);
}
DEV float b2f(u16 b) {
    union { unsigned u; float f; } v; v.u = ((unsigned)b) << 16;
    return v.f;
}
DEV float fast_tanh(float x) {
    float e = __expf(2.f * x);
    return 1.f - __fdividef(2.f, e + 1.f);
}
DEV float fast_sig(float x) {
    return __fdividef(1.f, 1.f + __expf(-x));
}
DEV void gload_lds(const u16* g, u16* l) {
    __builtin_amdgcn_global_load_lds((const __attribute__((address_space(1))) void*)g,
                                     (__attribute__((address_space(3))) void*)l, 16, 0, 0);
}

// ---------------------------------------------------------------------------
// Generic 128x128 MFMA GEMM (prologue GEMMs), BK=32, 4 waves (2x2).
// ---------------------------------------------------------------------------
template<bool A_F32, bool B_F32, bool B_KXN, bool OUT_BF16, bool BIAS>
__global__ __launch_bounds__(256) void gemm128(
    const void* __restrict__ Ap, int lda,
    const void* __restrict__ Bp, int ldb,
    void* __restrict__ Cp, int ldc,
    const float* __restrict__ bias, int K)
{
    __shared__ u16 As[128 * 40];
    __shared__ u16 Bs[128 * 40];
    const int tid = threadIdx.x;
    const int lane = tid & 63, wave = tid >> 6;
    const int wr = wave >> 1, wc = wave & 1;
    const int m0 = blockIdx.y * 128, n0 = blockIdx.x * 128;

    f32x4 acc[4][4];
#pragma unroll
    for (int m = 0; m < 4; ++m)
#pragma unroll
        for (int n = 0; n < 4; ++n)
            acc[m][n] = (f32x4){0.f, 0.f, 0.f, 0.f};

    for (int k0 = 0; k0 < K; k0 += 32) {
        __syncthreads();
        if (A_F32) {
            const float* A = (const float*)Ap;
#pragma unroll
            for (int i = 0; i < 4; ++i) {
                int c = tid + i * 256;
                int row = c >> 3, kc = (c & 7) * 4;
                float4 v = *(const float4*)&A[(size_t)(m0 + row) * lda + k0 + kc];
                ushort4 o; o.x = f2bu(v.x); o.y = f2bu(v.y); o.z = f2bu(v.z); o.w = f2bu(v.w);
                *(ushort4*)&As[row * 40 + kc] = o;
            }
        } else {
            const u16* A = (const u16*)Ap;
#pragma unroll
            for (int i = 0; i < 2; ++i) {
                int c = tid + i * 256;
                int row = c >> 2, kc = (c & 3) * 8;
                *(int4*)&As[row * 40 + kc] = *(const int4*)&A[(size_t)(m0 + row) * lda + k0 + kc];
            }
        }
        if (B_KXN) {
            const float* B = (const float*)Bp;
#pragma unroll
            for (int i = 0; i < 4; ++i) {
                int c = tid + i * 256;
                int kk = c >> 5, nc = (c & 31) * 4;
                float4 v = *(const float4*)&B[(size_t)(k0 + kk) * ldb + n0 + nc];
                Bs[(nc + 0) * 40 + kk] = f2bu(v.x);
                Bs[(nc + 1) * 40 + kk] = f2bu(v.y);
                Bs[(nc + 2) * 40 + kk] = f2bu(v.z);
                Bs[(nc + 3) * 40 + kk] = f2bu(v.w);
            }
        } else if (B_F32) {
            const float* B = (const float*)Bp;
#pragma unroll
            for (int i = 0; i < 4; ++i) {
                int c = tid + i * 256;
                int row = c >> 3, kc = (c & 7) * 4;
                float4 v = *(const float4*)&B[(size_t)(n0 + row) * ldb + k0 + kc];
                ushort4 o; o.x = f2bu(v.x); o.y = f2bu(v.y); o.z = f2bu(v.z); o.w = f2bu(v.w);
                *(ushort4*)&Bs[row * 40 + kc] = o;
            }
        } else {
            const u16* B = (const u16*)Bp;
#pragma unroll
            for (int i = 0; i < 2; ++i) {
                int c = tid + i * 256;
                int row = c >> 2, kc = (c & 3) * 8;
                *(int4*)&Bs[row * 40 + kc] = *(const int4*)&B[(size_t)(n0 + row) * ldb + k0 + kc];
            }
        }
        __syncthreads();
        const int fr = lane & 15, kq = (lane >> 4) * 8;
        bf16x8 af[4], bq[4];
#pragma unroll
        for (int m = 0; m < 4; ++m)
            af[m] = *(const bf16x8*)&As[(wr * 64 + m * 16 + fr) * 40 + kq];
#pragma unroll
        for (int n = 0; n < 4; ++n)
            bq[n] = *(const bf16x8*)&Bs[(wc * 64 + n * 16 + fr) * 40 + kq];
#pragma unroll
        for (int m = 0; m < 4; ++m)
#pragma unroll
            for (int n = 0; n < 4; ++n)
                acc[m][n] = __builtin_amdgcn_mfma_f32_16x16x32_bf16(af[m], bq[n], acc[m][n], 0, 0, 0);
    }
    const int fr = lane & 15, rq = (lane >> 4) * 4;
#pragma unroll
    for (int m = 0; m < 4; ++m) {
#pragma unroll
        for (int n = 0; n < 4; ++n) {
            int col = n0 + wc * 64 + n * 16 + fr;
            float bv = BIAS ? bias[col] : 0.f;
#pragma unroll
            for (int r = 0; r < 4; ++r) {
                int row = m0 + wr * 64 + m * 16 + rq + r;
                float v = acc[m][n][r] + bv;
                if (OUT_BF16) ((u16*)Cp)[(size_t)row * ldc + col] = f2bu(v);
                else          ((float*)Cp)[(size_t)row * ldc + col] = v;
            }
        }
    }
}

// ---------------------------------------------------------------------------
// Head GEMM: C[2048][32000] = A(bf16 [2048][1024]) @ B(bf16 [32000][1024])^T
// 256x256 tile, BK=32, 4 LDS buffers (128 KB), depth-3 counted-vmcnt pipeline:
// per K-step 2 stage issues, 16 MFMA, vmcnt(4) + ONE barrier. Never drains
// vmcnt to 0 until the tail. Swizzle: XOR key (row>>1)&3 on 16B slots of the
// 64B row -> 2-way bank access (free).
// ---------------------------------------------------------------------------
__global__ __launch_bounds__(1024) void gemm_head(const u16* __restrict__ A,
                                                  const u16* __restrict__ B,
                                                  float* __restrict__ C)
{
    __shared__ u16 As[4][256 * 32];   // 16 KB each
    __shared__ u16 Bs[4][256 * 32];   // 128 KB total
    const int tid = threadIdx.x, lane = tid & 63, wave = tid >> 6;  // 0..15
    const int wr = wave >> 2, wc = wave & 3;
    int bid = blockIdx.x;                       // 1000 = 8 * 125
    int nb = (bid & 7) * 125 + (bid >> 3);      // XCD-chunked
    const int m0 = (nb & 7) * 256;              // m fastest -> B-panel L2 reuse
    const int n0 = (nb >> 3) * 256;

    f32x4 acc[4][4];
#pragma unroll
    for (int m = 0; m < 4; ++m)
#pragma unroll
        for (int n = 0; n < 4; ++n)
            acc[m][n] = (f32x4){0.f, 0.f, 0.f, 0.f};

    // stage mapping: wave w stages rows w*16..w*16+15; lane -> row w*16+(lane>>2),
    // slot lane&3; source pre-swizzled by key (row>>1)&3.
    const int srow = wave * 16 + (lane >> 2);
    const int ge = (((lane & 3) ^ ((srow >> 1) & 3)) * 8);
    const int fr = lane & 15, kg = lane >> 4;

#define STAGE(bf, kt)                                                              \
    {                                                                              \
        gload_lds(&A[(size_t)(m0 + srow) * 1024 + (kt) * 32 + ge], &As[bf][wave * 512]); \
        gload_lds(&B[(size_t)(n0 + srow) * 1024 + (kt) * 32 + ge], &Bs[bf][wave * 512]); \
    }

    STAGE(0, 0);
    STAGE(1, 1);
    STAGE(2, 2);
    asm volatile("s_waitcnt vmcnt(4)" ::: "memory");   // buf0's 2 (oldest) landed
    __builtin_amdgcn_s_barrier();

    for (int kt = 0; kt < 32; ++kt) {
        const int cur = kt & 3;
        if (kt + 3 < 32) STAGE((kt + 3) & 3, kt + 3);  // flies under compute
        bf16x8 af[4], bq[4];
#pragma unroll
        for (int m = 0; m < 4; ++m) {
            const int row = wr * 64 + m * 16 + fr;
            af[m] = *(const bf16x8*)&As[cur][row * 32 + ((kg ^ ((row >> 1) & 3)) << 3)];
        }
#pragma unroll
        for (int n = 0; n < 4; ++n) {
            const int row = wc * 64 + n * 16 + fr;
            bq[n] = *(const bf16x8*)&Bs[cur][row * 32 + ((kg ^ ((row >> 1) & 3)) << 3)];
        }
#pragma unroll
        for (int m = 0; m < 4; ++m)
#pragma unroll
            for (int n = 0; n < 4; ++n)
                acc[m][n] = __builtin_amdgcn_mfma_f32_16x16x32_bf16(af[m], bq[n], acc[m][n], 0, 0, 0);
        // counted wait: ensure kt+1's buffer (oldest outstanding) landed
        if (kt + 3 < 32)      { asm volatile("s_waitcnt vmcnt(4)" ::: "memory"); }
        else if (kt + 2 < 32) { asm volatile("s_waitcnt vmcnt(2)" ::: "memory"); }
        else                  { asm volatile("s_waitcnt vmcnt(0)" ::: "memory"); }
        __builtin_amdgcn_s_barrier();   // arrival implies compute(cur) done + own stage landed
    }
#undef STAGE
    const int rq = kg * 4;
#pragma unroll
    for (int m = 0; m < 4; ++m)
#pragma unroll
        for (int n = 0; n < 4; ++n) {
            int col = n0 + wc * 64 + n * 16 + fr;
#pragma unroll
            for (int r = 0; r < 4; ++r)
                C[(size_t)(m0 + wr * 64 + m * 16 + rq + r) * 32000 + col] = acc[m][n][r];
        }
}

// ---------------------------------------------------------------------------
// Merged prologue conversions (WhidT packed k-major).
// ---------------------------------------------------------------------------
__global__ __launch_bounds__(256) void prep_k(
    const float* __restrict__ img, const float* __restrict__ Whh,
    const float* __restrict__ Whid, const float* __restrict__ Whead,
    const int* __restrict__ tok, const float* __restrict__ embed,
    const float* __restrict__ bih, const float* __restrict__ bhh,
    u16* __restrict__ img_bf, u16* __restrict__ Whh_bf,
    u16* __restrict__ WhidT, u16* __restrict__ Whead_bf,
    u16* __restrict__ emb_bf, float* __restrict__ bsum)
{
    const int bid = blockIdx.x;
    if (bid < 25088) {                       // img cvt
        int i = bid * 256 + threadIdx.x;
        float4 v = ((const float4*)img)[i];
        ushort4 o; o.x = f2bu(v.x); o.y = f2bu(v.y); o.z = f2bu(v.z); o.w = f2bu(v.w);
        ((ushort4*)img_bf)[i] = o;
    } else if (bid < 29184) {                // Whh cvt
        int i = (bid - 25088) * 256 + threadIdx.x;
        float4 v = ((const float4*)Whh)[i];
        ushort4 o; o.x = f2bu(v.x); o.y = f2bu(v.y); o.z = f2bu(v.z); o.w = f2bu(v.w);
        ((ushort4*)Whh_bf)[i] = o;
    } else if (bid < 29440) {                // WhidT pack
        int i = (bid - 29184) * 256 + threadIdx.x;   // 65536
        int a = i >> 8, k4 = (i & 255) * 4;
        float4 v = *(const float4*)&Whid[(size_t)a * 1024 + k4];
        ushort4 o; o.x = f2bu(v.x); o.y = f2bu(v.y); o.z = f2bu(v.z); o.w = f2bu(v.w);
        *(ushort4*)&WhidT[(size_t)(k4 >> 3) * 2048 + a * 8 + (k4 & 7)] = o;
    } else if (bid < 61440) {                // Whead cvt
        int i = (bid - 29440) * 256 + threadIdx.x;
        float4 v = ((const float4*)Whead)[i];
        ushort4 o; o.x = f2bu(v.x); o.y = f2bu(v.y); o.z = f2bu(v.z); o.w = f2bu(v.w);
        ((ushort4*)Whead_bf)[i] = o;
    } else if (bid < 65536) {                // emb gather, rows [t][b]
        int id = (bid - 61440) * 256 + threadIdx.x;
        int row = id >> 9, e = id & 511;
        int t = row >> 6, b = row & 63;
        int tk = tok[b * 32 + t];
        emb_bf[(size_t)row * 512 + e] = f2bu(embed[(size_t)tk * 512 + e]);
    } else {                                 // bias sum
        int i = (bid - 65536) * 256 + threadIdx.x;
        bsum[i] = bih[i] + bhh[i];
    }
}

// Fragment-pack gates weights: Wpk[bid][i][lane][8], i = K-iter (0..95).
__global__ __launch_bounds__(256) void pack_w(const u16* __restrict__ Wic,
                                              const u16* __restrict__ Whh,
                                              u16* __restrict__ Wpk)
{
    const int bid = blockIdx.y;
    const int t2 = blockIdx.x * 256 + threadIdx.x;   // 6144 = 96*64
    const int i = t2 >> 6, lane = t2 & 63;
    const int fr = lane & 15, kq = (lane >> 4) * 8;
    const int grow = ((fr >> 2) << 10) + bid * 4 + (fr & 3);
    const int k0 = i * 32;
    int4 v;
    if (k0 < 2048) v = *(const int4*)&Wic[(size_t)grow * 2048 + k0 + kq];
    else           v = *(const int4*)&Whh[(size_t)grow * 1024 + (k0 - 2048) + kq];
    *(int4*)&Wpk[((size_t)bid * 6144 + t2) * 8] = v;
}

// mean over n of img_bf
__global__ __launch_bounds__(256) void mean_k(const u16* __restrict__ img_bf, float* __restrict__ gT)
{
    int id = blockIdx.x * 256 + threadIdx.x;   // 65536
    int b = id >> 10;
    int d = (id & 1023) * 2;
    const u16* base = img_bf + (size_t)b * 196 * 2048 + d;
    float s0 = 0.f, s1 = 0.f;
#pragma unroll 4
    for (int n = 0; n < 196; ++n) {
        ushort2 v = *(const ushort2*)(base + (size_t)n * 2048);
        s0 += b2f(v.x);
        s1 += b2f(v.y);
    }
    gT[(d + 0) * 64 + b] = s0 * (1.f / 196.f);
    gT[(d + 1) * 64 + b] = s1 * (1.f / 196.f);
}

__global__ __launch_bounds__(256) void h0c0(const float* __restrict__ gT,
                                            const float* __restrict__ Wh0, const float* __restrict__ bh0,
                                            const float* __restrict__ Wc0, const float* __restrict__ bc0,
                                            float* __restrict__ c, u16* __restrict__ h0)
{
    int id = blockIdx.x * 256 + threadIdx.x;
    int b = id & 63, n = id >> 6;
    const float4* Wh = (const float4*)&Wh0[(size_t)n * 2048];
    const float4* Wc = (const float4*)&Wc0[(size_t)n * 2048];
    float s0 = 0.f, s1 = 0.f;
#pragma unroll 4
    for (int k4 = 0; k4 < 512; ++k4) {
        float4 wh = Wh[k4], wc = Wc[k4];
        float g0 = gT[(k4 * 4 + 0) * 64 + b];
        float g1 = gT[(k4 * 4 + 1) * 64 + b];
        float g2 = gT[(k4 * 4 + 2) * 64 + b];
        float g3 = gT[(k4 * 4 + 3) * 64 + b];
        s0 += wh.x * g0 + wh.y * g1 + wh.z * g2 + wh.w * g3;
        s1 += wc.x * g0 + wc.y * g1 + wc.z * g2 + wc.w * g3;
    }
    c[b * 1024 + n] = fast_tanh(s1 + bc0[n]);
    h0[(size_t)b * 1024 + n] = f2bu(fast_tanh(s0 + bh0[n]));
}

// ---------------------------------------------------------------------------
// Per-step kernel 1 (R13-proven): ph + scores + softmax + ctx quarter.
// grid 256 = (b,q), 1024 threads, single-wave softmax.
// ---------------------------------------------------------------------------
__global__ __launch_bounds__(1024) void attn_k(const u16* __restrict__ hb,      // [64][1024]
                                               const u16* __restrict__ WhidT,   // [128][256][8]
                                               const float* __restrict__ w_score,
                                               const u16* __restrict__ proj_bf, // [64*196][256]
                                               const u16* __restrict__ img_bf,  // [64][196][2048]
                                               u16* __restrict__ ctx_bf)        // [64][2048]
{
    const int b = blockIdx.x >> 2, q = blockIdx.x & 3;
    const int tid = threadIdx.x, lane = tid & 63, wave = tid >> 6;  // 0..15
    __shared__ float ph[256], ws[256], sc[256];
    __shared__ float hsh[1024];
    __shared__ float php[4][256];
    __shared__ float part[16][512];

    if (tid < 256) {
        ws[tid] = w_score[tid];
        sc[tid] = -1e30f;
    }
    hsh[tid] = b2f(hb[(size_t)b * 1024 + tid]);
    __syncthreads();

    // ph[a] = dot(h_b, Whid[a]) : thread (a = tid&255, ks = tid>>8)
    {
        const int a = tid & 255, ks = tid >> 8;
        float s = 0.f;
        const u16* wp = WhidT + a * 8;
#pragma unroll 8
        for (int j = 0; j < 32; ++j) {
            const int kb = ks * 32 + j;
            bf16x8 wv = *(const bf16x8*)(wp + (size_t)kb * 2048);
            const float* hk = &hsh[kb * 8];
#pragma unroll
            for (int i = 0; i < 8; ++i) s += hk[i] * (float)wv[i];
        }
        php[ks][a] = s;
    }
    __syncthreads();
    if (tid < 256) ph[tid] = php[0][tid] + php[1][tid] + php[2][tid] + php[3][tid];
    __syncthreads();

    // scores: wave w handles n = w, w+16, ...
    for (int n = wave; n < 196; n += 16) {
        const int a0 = lane * 4;
        ushort4 pv = *(const ushort4*)&proj_bf[((size_t)b * 196 + n) * 256 + a0];
        float s = ws[a0 + 0] * fast_tanh(b2f(pv.x) + ph[a0 + 0])
                + ws[a0 + 1] * fast_tanh(b2f(pv.y) + ph[a0 + 1])
                + ws[a0 + 2] * fast_tanh(b2f(pv.z) + ph[a0 + 2])
                + ws[a0 + 3] * fast_tanh(b2f(pv.w) + ph[a0 + 3]);
#pragma unroll
        for (int off = 32; off; off >>= 1) s += __shfl_xor(s, off, 64);
        if (lane == 0) sc[n] = s;
    }
    __syncthreads();

    // single-wave softmax over 256 (pad entries -1e30 -> e = 0)
    if (wave == 0) {
        float v0 = sc[lane], v1 = sc[lane + 64], v2 = sc[lane + 128], v3 = sc[lane + 192];
        float mx = fmaxf(fmaxf(v0, v1), fmaxf(v2, v3));
#pragma unroll
        for (int off = 32; off; off >>= 1) mx = fmaxf(mx, __shfl_xor(mx, off, 64));
        float e0 = __expf(v0 - mx), e1 = __expf(v1 - mx);
        float e2 = __expf(v2 - mx), e3 = __expf(v3 - mx);
        float s = e0 + e1 + e2 + e3;
#pragma unroll
        for (int off = 32; off; off >>= 1) s += __shfl_xor(s, off, 64);
        const float inv = __fdividef(1.f, s);
        sc[lane] = e0 * inv;
        sc[lane + 64] = e1 * inv;
        sc[lane + 128] = e2 * inv;
        sc[lane + 192] = e3 * inv;
    }
    __syncthreads();

    // ctx quarter: 512 cols; group gid (64 groups of 8 cols), 16-way n-split
    const int gid = tid >> 4, st = tid & 15;
    const int c0 = q * 512 + gid * 8;
    const u16* base = img_bf + ((size_t)b * 196) * 2048 + c0;
    float a[8];
#pragma unroll
    for (int i = 0; i < 8; ++i) a[i] = 0.f;
    for (int n = st; n < 196; n += 16) {
        bf16x8 v = *(const bf16x8*)(base + (size_t)n * 2048);
        float wgt = sc[n];
#pragma unroll
        for (int i = 0; i < 8; ++i) a[i] += wgt * (float)v[i];
    }
#pragma unroll
    for (int i = 0; i < 8; ++i) part[st][gid * 8 + i] = a[i];
    __syncthreads();
    if (tid < 512) {
        const int col = tid;
        float v = 0.f;
#pragma unroll
        for (int s16 = 0; s16 < 16; ++s16) v += part[s16][col];
        ctx_bf[(size_t)b * 2048 + q * 512 + col] = f2bu(v);
    }
}

// ---------------------------------------------------------------------------
// Per-step kernel 2 (R9-proven): gates MFMA + LSTM pointwise.
// grid 256 x 1024 threads, 16-wave K-split (192 each).
// ---------------------------------------------------------------------------
__global__ __launch_bounds__(1024) void gates_k(const u16* __restrict__ ctx_bf,  // [64][2048]
                                                const u16* __restrict__ hb,      // [64][1024]
                                                const u16* __restrict__ Wpk,     // [256][96][64][8]
                                                const float* __restrict__ xg,    // [32][64][4096]
                                                float* __restrict__ cbuf,        // [64][1024]
                                                u16* __restrict__ h_nxt,         // [64][1024]
                                                u16* __restrict__ h_all,         // [2048][1024]
                                                int t)
{
    const int tid = threadIdx.x, lane = tid & 63, wave = tid >> 6;  // 0..15
    const int fr = lane & 15, kq = (lane >> 4) * 8, rq = (lane >> 4) * 4;
    const int hc0 = blockIdx.x * 4;
    const u16* Wblk = Wpk + (size_t)blockIdx.x * 49152 + lane * 8;  // [96][64][8]
    __shared__ float red[16][64][16];

    f32x4 acc[4];
#pragma unroll
    for (int m = 0; m < 4; ++m) acc[m] = (f32x4){0.f, 0.f, 0.f, 0.f};

    const int kbeg = wave * 192, kend = kbeg + 192;
    const int cend = kend < 2048 ? kend : 2048;
#pragma unroll 2
    for (int k0 = kbeg; k0 < cend; k0 += 32) {
        bf16x8 bq = *(const bf16x8*)&Wblk[(size_t)(k0 >> 5) * 512];
#pragma unroll
        for (int m = 0; m < 4; ++m) {
            bf16x8 af = *(const bf16x8*)&ctx_bf[(size_t)(m * 16 + fr) * 2048 + k0 + kq];
            acc[m] = __builtin_amdgcn_mfma_f32_16x16x32_bf16(af, bq, acc[m], 0, 0, 0);
        }
    }
    const int hbeg = kbeg > 2048 ? kbeg - 2048 : 0;
    const int hend = kend > 2048 ? kend - 2048 : 0;
#pragma unroll 2
    for (int kh = hbeg; kh < hend; kh += 32) {
        bf16x8 bq = *(const bf16x8*)&Wblk[(size_t)((kh + 2048) >> 5) * 512];
#pragma unroll
        for (int m = 0; m < 4; ++m) {
            bf16x8 af = *(const bf16x8*)&hb[(size_t)(m * 16 + fr) * 1024 + kh + kq];
            acc[m] = __builtin_amdgcn_mfma_f32_16x16x32_bf16(af, bq, acc[m], 0, 0, 0);
        }
    }
#pragma unroll
    for (int m = 0; m < 4; ++m)
#pragma unroll
        for (int r = 0; r < 4; ++r)
            red[wave][m * 16 + rq + r][fr] = acc[m][r];
    __syncthreads();

    if (tid < 256) {
        const int bb = tid >> 2, j = tid & 3;
        const int col = hc0 + j;
        float G[4];
#pragma unroll
        for (int g = 0; g < 4; ++g) {
            const int f2 = g * 4 + j;
            float s = 0.f;
#pragma unroll
            for (int w16 = 0; w16 < 16; ++w16) s += red[w16][bb][f2];
            G[g] = s + xg[((size_t)t * 64 + bb) * 4096 + g * 1024 + col];
        }
        float ig = fast_sig(G[0]), fg = fast_sig(G[1]);
        float gv = fast_tanh(G[2]), og = fast_sig(G[3]);
        float cp = cbuf[bb * 1024 + col];
        float cn = fg * cp + ig * gv;
        cbuf[bb * 1024 + col] = cn;
        u16 hv = f2bu(og * fast_tanh(cn));
        h_nxt[(size_t)bb * 1024 + col] = hv;
        h_all[((size_t)bb * 32 + t) * 1024 + col] = hv;
    }
}

// ---------------------------------------------------------------------------
extern "C" void kernel_launch(void* const* d_in, const int* in_sizes, int n_in,
                              void* d_out, int out_size, void* d_ws, size_t ws_size,
                              hipStream_t stream)
{
    const float* img     = (const float*)d_in[0];
    const int*   tok     = (const int*)d_in[1];
    const float* embed   = (const float*)d_in[2];
    const float* W_head1 = (const float*)d_in[3];
    const float* W_ih    = (const float*)d_in[4];
    const float* W_hh    = (const float*)d_in[5];
    const float* b_ih    = (const float*)d_in[6];
    const float* b_hh    = (const float*)d_in[7];
    const float* W_head  = (const float*)d_in[8];
    const float* W_img   = (const float*)d_in[9];
    const float* W_hid   = (const float*)d_in[10];
    const float* w_score = (const float*)d_in[11];
    const float* W_h0    = (const float*)d_in[12];
    const float* b_h0    = (const float*)d_in[13];
    const float* W_c0    = (const float*)d_in[14];
    const float* b_c0    = (const float*)d_in[15];
    float* out = (float*)d_out;

    char* w = (char*)d_ws;
    size_t off = 0;
    auto alloc = [&](size_t bytes) { char* p = w + off; off += (bytes + 255) & ~(size_t)255; return p; };

    u16*   Wic      = (u16*)alloc(4096ULL * 2048 * 2);
    u16*   Whh_bf   = (u16*)alloc(4096ULL * 1024 * 2);
    u16*   Wpk      = (u16*)alloc(256ULL * 96 * 64 * 8 * 2);
    u16*   WhidT    = (u16*)alloc(256ULL * 1024 * 2);
    u16*   Whead_bf = (u16*)alloc(32000ULL * 1024 * 2);
    u16*   img_bf   = (u16*)alloc(64ULL * 196 * 2048 * 2);
    float* xg       = (float*)alloc(2048ULL * 4096 * 4);
    u16*   proj_bf  = (u16*)alloc(64ULL * 196 * 256 * 2);
    u16*   emb_bf   = (u16*)alloc(2048ULL * 512 * 2);
    u16*   xe       = (u16*)alloc(2048ULL * 512 * 2);
    float* gT       = (float*)alloc(2048ULL * 64 * 4);
    float* cbuf     = (float*)alloc(64ULL * 1024 * 4);
    u16*   hbuf     = (u16*)alloc(2ULL * 64 * 1024 * 2);
    u16*   ctx_bf   = (u16*)alloc(64ULL * 2048 * 2);
    u16*   h_all    = (u16*)alloc(2048ULL * 1024 * 2);
    float* bsum     = (float*)alloc(4096ULL * 4);
    (void)ws_size; (void)in_sizes; (void)n_in; (void)out_size;

    // ---- prologue (consolidated)
    prep_k<<<dim3(65552), dim3(256), 0, stream>>>(img, W_hh, W_hid, W_head, tok, embed,
                                                  b_ih, b_hh, img_bf, Whh_bf, WhidT,
                                                  Whead_bf, emb_bf, bsum);
    mean_k<<<dim3(256), dim3(256), 0, stream>>>(img_bf, gT);
    h0c0<<<dim3(256), dim3(256), 0, stream>>>(gT, W_h0, b_h0, W_c0, b_c0, cbuf, hbuf);

    // xe = emb @ Wa^T (Wa = W_head1[:, :512]); rows [t][b]
    gemm128<false, true, false, true, false><<<dim3(4, 16), dim3(256), 0, stream>>>(
        emb_bf, 512, W_head1, 2560, xe, 512, nullptr, 512);
    // xg = xe @ W_ih^T + (b_ih + b_hh); rows [t][b]
    gemm128<false, true, false, false, true><<<dim3(32, 16), dim3(256), 0, stream>>>(
        xe, 512, W_ih, 512, xg, 4096, bsum, 512);
    // Wic = W_ih @ W_head1[:, 512:]
    gemm128<true, true, true, true, false><<<dim3(16, 32), dim3(256), 0, stream>>>(
        W_ih, 512, W_head1 + 512, 2560, Wic, 2048, nullptr, 512);
    // proj_bf = img_bf @ W_img^T (bf16 out)
    gemm128<false, true, false, true, false><<<dim3(2, 98), dim3(256), 0, stream>>>(
        img_bf, 2048, W_img, 2048, proj_bf, 256, nullptr, 2048);
    // fragment-pack gates weights (needs Wic + Whh_bf)
    pack_w<<<dim3(24, 256), dim3(256), 0, stream>>>(Wic, Whh_bf, Wpk);

    // ---- recurrence: 2 kernels per step (R13 structure)
    for (int t = 0; t < 32; ++t) {
        u16* hb = hbuf + (size_t)(t & 1) * 65536;
        u16* hn = hbuf + (size_t)((t + 1) & 1) * 65536;
        attn_k<<<dim3(256), dim3(1024), 0, stream>>>(hb, WhidT, w_score, proj_bf, img_bf, ctx_bf);
        gates_k<<<dim3(256), dim3(1024), 0, stream>>>(ctx_bf, hb, Wpk, xg, cbuf, hn, h_all, t);
    }

    // ---- logits: out = h_all @ W_head^T (BK=32 depth-3 counted pipeline)
    gemm_head<<<dim3(1000), dim3(1024), 0, stream>>>(h_all, Whead_bf, out);
}

// Round 16
// 1902.924 us; speedup vs baseline: 1.0313x; 1.0182x over previous
//
#include <hip/hip_runtime.h>
#include <stdint.h>

typedef unsigned short u16;
typedef __bf16 bf16x8 __attribute__((ext_vector_type(8)));
typedef float f32x4 __attribute__((ext_vector_type(4)));

#define DEV static __device__ __forceinline__

DEV u16 f2bu(float f) {
    union { float f; unsigned u; } v; v.f = f;
    unsigned r = v.u + 0x7FFFu + ((v.u >> 16) & 1u);
    return (u16)(r >> 16);
}
DEV float b2f(u16 b) {
    union { unsigned u; float f; } v; v.u = ((unsigned)b) << 16;
    return v.f;
}
DEV float fast_tanh(float x) {
    float e = __expf(2.f * x);
    return 1.f - __fdividef(2.f, e + 1.f);
}
DEV float fast_sig(float x) {
    return __fdividef(1.f, 1.f + __expf(-x));
}
DEV void gload_lds(const u16* g, u16* l) {
    __builtin_amdgcn_global_load_lds((const __attribute__((address_space(1))) void*)g,
                                     (__attribute__((address_space(3))) void*)l, 16, 0, 0);
}

// ---------------------------------------------------------------------------
// Generic 128x128 MFMA GEMM (prologue GEMMs), BK=32, 4 waves (2x2).
// ---------------------------------------------------------------------------
template<bool A_F32, bool B_F32, bool B_KXN, bool OUT_BF16, bool BIAS>
__global__ __launch_bounds__(256) void gemm128(
    const void* __restrict__ Ap, int lda,
    const void* __restrict__ Bp, int ldb,
    void* __restrict__ Cp, int ldc,
    const float* __restrict__ bias, int K)
{
    __shared__ u16 As[128 * 40];
    __shared__ u16 Bs[128 * 40];
    const int tid = threadIdx.x;
    const int lane = tid & 63, wave = tid >> 6;
    const int wr = wave >> 1, wc = wave & 1;
    const int m0 = blockIdx.y * 128, n0 = blockIdx.x * 128;

    f32x4 acc[4][4];
#pragma unroll
    for (int m = 0; m < 4; ++m)
#pragma unroll
        for (int n = 0; n < 4; ++n)
            acc[m][n] = (f32x4){0.f, 0.f, 0.f, 0.f};

    for (int k0 = 0; k0 < K; k0 += 32) {
        __syncthreads();
        if (A_F32) {
            const float* A = (const float*)Ap;
#pragma unroll
            for (int i = 0; i < 4; ++i) {
                int c = tid + i * 256;
                int row = c >> 3, kc = (c & 7) * 4;
                float4 v = *(const float4*)&A[(size_t)(m0 + row) * lda + k0 + kc];
                ushort4 o; o.x = f2bu(v.x); o.y = f2bu(v.y); o.z = f2bu(v.z); o.w = f2bu(v.w);
                *(ushort4*)&As[row * 40 + kc] = o;
            }
        } else {
            const u16* A = (const u16*)Ap;
#pragma unroll
            for (int i = 0; i < 2; ++i) {
                int c = tid + i * 256;
                int row = c >> 2, kc = (c & 3) * 8;
                *(int4*)&As[row * 40 + kc] = *(const int4*)&A[(size_t)(m0 + row) * lda + k0 + kc];
            }
        }
        if (B_KXN) {
            const float* B = (const float*)Bp;
#pragma unroll
            for (int i = 0; i < 4; ++i) {
                int c = tid + i * 256;
                int kk = c >> 5, nc = (c & 31) * 4;
                float4 v = *(const float4*)&B[(size_t)(k0 + kk) * ldb + n0 + nc];
                Bs[(nc + 0) * 40 + kk] = f2bu(v.x);
                Bs[(nc + 1) * 40 + kk] = f2bu(v.y);
                Bs[(nc + 2) * 40 + kk] = f2bu(v.z);
                Bs[(nc + 3) * 40 + kk] = f2bu(v.w);
            }
        } else if (B_F32) {
            const float* B = (const float*)Bp;
#pragma unroll
            for (int i = 0; i < 4; ++i) {
                int c = tid + i * 256;
                int row = c >> 3, kc = (c & 7) * 4;
                float4 v = *(const float4*)&B[(size_t)(n0 + row) * ldb + k0 + kc];
                ushort4 o; o.x = f2bu(v.x); o.y = f2bu(v.y); o.z = f2bu(v.z); o.w = f2bu(v.w);
                *(ushort4*)&Bs[row * 40 + kc] = o;
            }
        } else {
            const u16* B = (const u16*)Bp;
#pragma unroll
            for (int i = 0; i < 2; ++i) {
                int c = tid + i * 256;
                int row = c >> 2, kc = (c & 3) * 8;
                *(int4*)&Bs[row * 40 + kc] = *(const int4*)&B[(size_t)(n0 + row) * ldb + k0 + kc];
            }
        }
        __syncthreads();
        const int fr = lane & 15, kq = (lane >> 4) * 8;
        bf16x8 af[4], bq[4];
#pragma unroll
        for (int m = 0; m < 4; ++m)
            af[m] = *(const bf16x8*)&As[(wr * 64 + m * 16 + fr) * 40 + kq];
#pragma unroll
        for (int n = 0; n < 4; ++n)
            bq[n] = *(const bf16x8*)&Bs[(wc * 64 + n * 16 + fr) * 40 + kq];
#pragma unroll
        for (int m = 0; m < 4; ++m)
#pragma unroll
            for (int n = 0; n < 4; ++n)
                acc[m][n] = __builtin_amdgcn_mfma_f32_16x16x32_bf16(af[m], bq[n], acc[m][n], 0, 0, 0);
    }
    const int fr = lane & 15, rq = (lane >> 4) * 4;
#pragma unroll
    for (int m = 0; m < 4; ++m) {
#pragma unroll
        for (int n = 0; n < 4; ++n) {
            int col = n0 + wc * 64 + n * 16 + fr;
            float bv = BIAS ? bias[col] : 0.f;
#pragma unroll
            for (int r = 0; r < 4; ++r) {
                int row = m0 + wr * 64 + m * 16 + rq + r;
                float v = acc[m][n][r] + bv;
                if (OUT_BF16) ((u16*)Cp)[(size_t)row * ldc + col] = f2bu(v);
                else          ((float*)Cp)[(size_t)row * ldc + col] = v;
            }
        }
    }
}

// ---------------------------------------------------------------------------
// Head GEMM (R13-proven, 168 us): 256x256, BK=64, 16 waves, counted-vmcnt
// depth-2 pipeline, XOR swizzle (0 conflicts).
// ---------------------------------------------------------------------------
__global__ __launch_bounds__(1024) void gemm_head(const u16* __restrict__ A,
                                                  const u16* __restrict__ B,
                                                  float* __restrict__ C)
{
    __shared__ u16 As[2][256 * 64];
    __shared__ u16 Bs[2][256 * 64];
    const int tid = threadIdx.x, lane = tid & 63, wave = tid >> 6;  // 0..15
    const int wr = wave >> 2, wc = wave & 3;
    int bid = blockIdx.x;                       // 1000 = 8 * 125
    int nb = (bid & 7) * 125 + (bid >> 3);      // XCD-chunked
    const int m0 = (nb & 7) * 256;              // m fastest -> B-panel L2 reuse
    const int n0 = (nb >> 3) * 256;

    f32x4 acc[4][4];
#pragma unroll
    for (int m = 0; m < 4; ++m)
#pragma unroll
        for (int n = 0; n < 4; ++n)
            acc[m][n] = (f32x4){0.f, 0.f, 0.f, 0.f};

    const int srg = lane >> 3;
    const int sslot = lane & 7;
    const int ge = (sslot ^ srg) * 8;
    const int fr = lane & 15, kg = lane >> 4;

#define STAGE(bf, kt)                                                              \
    {                                                                              \
        const int k0s = (kt) * 64;                                                 \
        _Pragma("unroll")                                                          \
        for (int j = 0; j < 2; ++j) {                                              \
            const int g = wave * 2 + j;                                            \
            gload_lds(&A[(size_t)(m0 + g * 8 + srg) * 1024 + k0s + ge],            \
                      &As[bf][g * 8 * 64]);                                        \
            gload_lds(&B[(size_t)(n0 + g * 8 + srg) * 1024 + k0s + ge],            \
                      &Bs[bf][g * 8 * 64]);                                        \
        }                                                                          \
    }

    STAGE(0, 0);
    STAGE(1, 1);
    asm volatile("s_waitcnt vmcnt(4)" ::: "memory");
    __builtin_amdgcn_s_barrier();

    for (int kt = 0; kt < 16; ++kt) {
        const int cur = kt & 1;
#pragma unroll
        for (int kk = 0; kk < 2; ++kk) {
            const int sl = kk * 4 + kg;
            bf16x8 af[4], bq[4];
#pragma unroll
            for (int m = 0; m < 4; ++m) {
                const int row = wr * 64 + m * 16 + fr;
                af[m] = *(const bf16x8*)&As[cur][row * 64 + ((sl ^ (row & 7)) << 3)];
            }
#pragma unroll
            for (int n = 0; n < 4; ++n) {
                const int row = wc * 64 + n * 16 + fr;
                bq[n] = *(const bf16x8*)&Bs[cur][row * 64 + ((sl ^ (row & 7)) << 3)];
            }
#pragma unroll
            for (int m = 0; m < 4; ++m)
#pragma unroll
                for (int n = 0; n < 4; ++n)
                    acc[m][n] = __builtin_amdgcn_mfma_f32_16x16x32_bf16(af[m], bq[n], acc[m][n], 0, 0, 0);
        }
        __builtin_amdgcn_s_barrier();
        if (kt + 2 < 16) {
            STAGE(cur, kt + 2);
            asm volatile("s_waitcnt vmcnt(4)" ::: "memory");
        } else {
            asm volatile("s_waitcnt vmcnt(0)" ::: "memory");
        }
        __builtin_amdgcn_s_barrier();
    }
#undef STAGE
    const int rq = kg * 4;
#pragma unroll
    for (int m = 0; m < 4; ++m)
#pragma unroll
        for (int n = 0; n < 4; ++n) {
            int col = n0 + wc * 64 + n * 16 + fr;
#pragma unroll
            for (int r = 0; r < 4; ++r)
                C[(size_t)(m0 + wr * 64 + m * 16 + rq + r) * 32000 + col] = acc[m][n][r];
        }
}

// ---------------------------------------------------------------------------
// Merged prologue conversions (WhidT packed k-major).
// ---------------------------------------------------------------------------
__global__ __launch_bounds__(256) void prep_k(
    const float* __restrict__ img, const float* __restrict__ Whh,
    const float* __restrict__ Whid, const float* __restrict__ Whead,
    const int* __restrict__ tok, const float* __restrict__ embed,
    const float* __restrict__ bih, const float* __restrict__ bhh,
    u16* __restrict__ img_bf, u16* __restrict__ Whh_bf,
    u16* __restrict__ WhidT, u16* __restrict__ Whead_bf,
    u16* __restrict__ emb_bf, float* __restrict__ bsum)
{
    const int bid = blockIdx.x;
    if (bid < 25088) {                       // img cvt
        int i = bid * 256 + threadIdx.x;
        float4 v = ((const float4*)img)[i];
        ushort4 o; o.x = f2bu(v.x); o.y = f2bu(v.y); o.z = f2bu(v.z); o.w = f2bu(v.w);
        ((ushort4*)img_bf)[i] = o;
    } else if (bid < 29184) {                // Whh cvt
        int i = (bid - 25088) * 256 + threadIdx.x;
        float4 v = ((const float4*)Whh)[i];
        ushort4 o; o.x = f2bu(v.x); o.y = f2bu(v.y); o.z = f2bu(v.z); o.w = f2bu(v.w);
        ((ushort4*)Whh_bf)[i] = o;
    } else if (bid < 29440) {                // WhidT pack
        int i = (bid - 29184) * 256 + threadIdx.x;   // 65536
        int a = i >> 8, k4 = (i & 255) * 4;
        float4 v = *(const float4*)&Whid[(size_t)a * 1024 + k4];
        ushort4 o; o.x = f2bu(v.x); o.y = f2bu(v.y); o.z = f2bu(v.z); o.w = f2bu(v.w);
        *(ushort4*)&WhidT[(size_t)(k4 >> 3) * 2048 + a * 8 + (k4 & 7)] = o;
    } else if (bid < 61440) {                // Whead cvt
        int i = (bid - 29440) * 256 + threadIdx.x;
        float4 v = ((const float4*)Whead)[i];
        ushort4 o; o.x = f2bu(v.x); o.y = f2bu(v.y); o.z = f2bu(v.z); o.w = f2bu(v.w);
        ((ushort4*)Whead_bf)[i] = o;
    } else if (bid < 65536) {                // emb gather, rows [t][b]
        int id = (bid - 61440) * 256 + threadIdx.x;
        int row = id >> 9, e = id & 511;
        int t = row >> 6, b = row & 63;
        int tk = tok[b * 32 + t];
        emb_bf[(size_t)row * 512 + e] = f2bu(embed[(size_t)tk * 512 + e]);
    } else {                                 // bias sum
        int i = (bid - 65536) * 256 + threadIdx.x;
        bsum[i] = bih[i] + bhh[i];
    }
}

// Fragment-pack gates weights: Wpk[bid][i][lane][8], i = K-iter (0..95).
__global__ __launch_bounds__(256) void pack_w(const u16* __restrict__ Wic,
                                              const u16* __restrict__ Whh,
                                              u16* __restrict__ Wpk)
{
    const int bid = blockIdx.y;
    const int t2 = blockIdx.x * 256 + threadIdx.x;   // 6144 = 96*64
    const int i = t2 >> 6, lane = t2 & 63;
    const int fr = lane & 15, kq = (lane >> 4) * 8;
    const int grow = ((fr >> 2) << 10) + bid * 4 + (fr & 3);
    const int k0 = i * 32;
    int4 v;
    if (k0 < 2048) v = *(const int4*)&Wic[(size_t)grow * 2048 + k0 + kq];
    else           v = *(const int4*)&Whh[(size_t)grow * 1024 + (k0 - 2048) + kq];
    *(int4*)&Wpk[((size_t)bid * 6144 + t2) * 8] = v;
}

// mean over n of img_bf
__global__ __launch_bounds__(256) void mean_k(const u16* __restrict__ img_bf, float* __restrict__ gT)
{
    int id = blockIdx.x * 256 + threadIdx.x;   // 65536
    int b = id >> 10;
    int d = (id & 1023) * 2;
    const u16* base = img_bf + (size_t)b * 196 * 2048 + d;
    float s0 = 0.f, s1 = 0.f;
#pragma unroll 4
    for (int n = 0; n < 196; ++n) {
        ushort2 v = *(const ushort2*)(base + (size_t)n * 2048);
        s0 += b2f(v.x);
        s1 += b2f(v.y);
    }
    gT[(d + 0) * 64 + b] = s0 * (1.f / 196.f);
    gT[(d + 1) * 64 + b] = s1 * (1.f / 196.f);
}

__global__ __launch_bounds__(256) void h0c0(const float* __restrict__ gT,
                                            const float* __restrict__ Wh0, const float* __restrict__ bh0,
                                            const float* __restrict__ Wc0, const float* __restrict__ bc0,
                                            float* __restrict__ c, u16* __restrict__ h0)
{
    int id = blockIdx.x * 256 + threadIdx.x;
    int b = id & 63, n = id >> 6;
    const float4* Wh = (const float4*)&Wh0[(size_t)n * 2048];
    const float4* Wc = (const float4*)&Wc0[(size_t)n * 2048];
    float s0 = 0.f, s1 = 0.f;
#pragma unroll 4
    for (int k4 = 0; k4 < 512; ++k4) {
        float4 wh = Wh[k4], wc = Wc[k4];
        float g0 = gT[(k4 * 4 + 0) * 64 + b];
        float g1 = gT[(k4 * 4 + 1) * 64 + b];
        float g2 = gT[(k4 * 4 + 2) * 64 + b];
        float g3 = gT[(k4 * 4 + 3) * 64 + b];
        s0 += wh.x * g0 + wh.y * g1 + wh.z * g2 + wh.w * g3;
        s1 += wc.x * g0 + wc.y * g1 + wc.z * g2 + wc.w * g3;
    }
    c[b * 1024 + n] = fast_tanh(s1 + bc0[n]);
    h0[(size_t)b * 1024 + n] = f2bu(fast_tanh(s0 + bh0[n]));
}

// ---------------------------------------------------------------------------
// Per-step kernel 1 (R13-proven): ph + scores + softmax + ctx quarter.
// grid 256 = (b,q), 1024 threads, single-wave softmax.
// ---------------------------------------------------------------------------
__global__ __launch_bounds__(1024) void attn_k(const u16* __restrict__ hb,      // [64][1024]
                                               const u16* __restrict__ WhidT,   // [128][256][8]
                                               const float* __restrict__ w_score,
                                               const u16* __restrict__ proj_bf, // [64*196][256]
                                               const u16* __restrict__ img_bf,  // [64][196][2048]
                                               u16* __restrict__ ctx_bf)        // [64][2048]
{
    const int b = blockIdx.x >> 2, q = blockIdx.x & 3;
    const int tid = threadIdx.x, lane = tid & 63, wave = tid >> 6;  // 0..15
    __shared__ float ph[256], ws[256], sc[256];
    __shared__ float hsh[1024];
    __shared__ float php[4][256];
    __shared__ float part[16][512];

    if (tid < 256) {
        ws[tid] = w_score[tid];
        sc[tid] = -1e30f;
    }
    hsh[tid] = b2f(hb[(size_t)b * 1024 + tid]);
    __syncthreads();

    // ph[a] = dot(h_b, Whid[a]) : thread (a = tid&255, ks = tid>>8)
    {
        const int a = tid & 255, ks = tid >> 8;
        float s = 0.f;
        const u16* wp = WhidT + a * 8;
#pragma unroll 8
        for (int j = 0; j < 32; ++j) {
            const int kb = ks * 32 + j;
            bf16x8 wv = *(const bf16x8*)(wp + (size_t)kb * 2048);
            const float* hk = &hsh[kb * 8];
#pragma unroll
            for (int i = 0; i < 8; ++i) s += hk[i] * (float)wv[i];
        }
        php[ks][a] = s;
    }
    __syncthreads();
    if (tid < 256) ph[tid] = php[0][tid] + php[1][tid] + php[2][tid] + php[3][tid];
    __syncthreads();

    // scores: wave w handles n = w, w+16, ...
    for (int n = wave; n < 196; n += 16) {
        const int a0 = lane * 4;
        ushort4 pv = *(const ushort4*)&proj_bf[((size_t)b * 196 + n) * 256 + a0];
        float s = ws[a0 + 0] * fast_tanh(b2f(pv.x) + ph[a0 + 0])
                + ws[a0 + 1] * fast_tanh(b2f(pv.y) + ph[a0 + 1])
                + ws[a0 + 2] * fast_tanh(b2f(pv.z) + ph[a0 + 2])
                + ws[a0 + 3] * fast_tanh(b2f(pv.w) + ph[a0 + 3]);
#pragma unroll
        for (int off = 32; off; off >>= 1) s += __shfl_xor(s, off, 64);
        if (lane == 0) sc[n] = s;
    }
    __syncthreads();

    // single-wave softmax over 256 (pad entries -1e30 -> e = 0)
    if (wave == 0) {
        float v0 = sc[lane], v1 = sc[lane + 64], v2 = sc[lane + 128], v3 = sc[lane + 192];
        float mx = fmaxf(fmaxf(v0, v1), fmaxf(v2, v3));
#pragma unroll
        for (int off = 32; off; off >>= 1) mx = fmaxf(mx, __shfl_xor(mx, off, 64));
        float e0 = __expf(v0 - mx), e1 = __expf(v1 - mx);
        float e2 = __expf(v2 - mx), e3 = __expf(v3 - mx);
        float s = e0 + e1 + e2 + e3;
#pragma unroll
        for (int off = 32; off; off >>= 1) s += __shfl_xor(s, off, 64);
        const float inv = __fdividef(1.f, s);
        sc[lane] = e0 * inv;
        sc[lane + 64] = e1 * inv;
        sc[lane + 128] = e2 * inv;
        sc[lane + 192] = e3 * inv;
    }
    __syncthreads();

    // ctx quarter: 512 cols; group gid (64 groups of 8 cols), 16-way n-split
    const int gid = tid >> 4, st = tid & 15;
    const int c0 = q * 512 + gid * 8;
    const u16* base = img_bf + ((size_t)b * 196) * 2048 + c0;
    float a[8];
#pragma unroll
    for (int i = 0; i < 8; ++i) a[i] = 0.f;
    for (int n = st; n < 196; n += 16) {
        bf16x8 v = *(const bf16x8*)(base + (size_t)n * 2048);
        float wgt = sc[n];
#pragma unroll
        for (int i = 0; i < 8; ++i) a[i] += wgt * (float)v[i];
    }
#pragma unroll
    for (int i = 0; i < 8; ++i) part[st][gid * 8 + i] = a[i];
    __syncthreads();
    if (tid < 512) {
        const int col = tid;
        float v = 0.f;
#pragma unroll
        for (int s16 = 0; s16 < 16; ++s16) v += part[s16][col];
        ctx_bf[(size_t)b * 2048 + q * 512 + col] = f2bu(v);
    }
}

// ---------------------------------------------------------------------------
// Per-step kernel 2 (R9-proven + T5 setprio around MFMA):
// gates MFMA + LSTM pointwise. grid 256 x 1024 threads, 16-wave K-split.
// ---------------------------------------------------------------------------
__global__ __launch_bounds__(1024) void gates_k(const u16* __restrict__ ctx_bf,  // [64][2048]
                                                const u16* __restrict__ hb,      // [64][1024]
                                                const u16* __restrict__ Wpk,     // [256][96][64][8]
                                                const float* __restrict__ xg,    // [32][64][4096]
                                                float* __restrict__ cbuf,        // [64][1024]
                                                u16* __restrict__ h_nxt,         // [64][1024]
                                                u16* __restrict__ h_all,         // [2048][1024]
                                                int t)
{
    const int tid = threadIdx.x, lane = tid & 63, wave = tid >> 6;  // 0..15
    const int fr = lane & 15, kq = (lane >> 4) * 8, rq = (lane >> 4) * 4;
    const int hc0 = blockIdx.x * 4;
    const u16* Wblk = Wpk + (size_t)blockIdx.x * 49152 + lane * 8;  // [96][64][8]
    __shared__ float red[16][64][16];

    f32x4 acc[4];
#pragma unroll
    for (int m = 0; m < 4; ++m) acc[m] = (f32x4){0.f, 0.f, 0.f, 0.f};

    const int kbeg = wave * 192, kend = kbeg + 192;
    const int cend = kend < 2048 ? kend : 2048;
    __builtin_amdgcn_s_setprio(1);
#pragma unroll 2
    for (int k0 = kbeg; k0 < cend; k0 += 32) {
        bf16x8 bq = *(const bf16x8*)&Wblk[(size_t)(k0 >> 5) * 512];
#pragma unroll
        for (int m = 0; m < 4; ++m) {
            bf16x8 af = *(const bf16x8*)&ctx_bf[(size_t)(m * 16 + fr) * 2048 + k0 + kq];
            acc[m] = __builtin_amdgcn_mfma_f32_16x16x32_bf16(af, bq, acc[m], 0, 0, 0);
        }
    }
    const int hbeg = kbeg > 2048 ? kbeg - 2048 : 0;
    const int hend = kend > 2048 ? kend - 2048 : 0;
#pragma unroll 2
    for (int kh = hbeg; kh < hend; kh += 32) {
        bf16x8 bq = *(const bf16x8*)&Wblk[(size_t)((kh + 2048) >> 5) * 512];
#pragma unroll
        for (int m = 0; m < 4; ++m) {
            bf16x8 af = *(const bf16x8*)&hb[(size_t)(m * 16 + fr) * 1024 + kh + kq];
            acc[m] = __builtin_amdgcn_mfma_f32_16x16x32_bf16(af, bq, acc[m], 0, 0, 0);
        }
    }
    __builtin_amdgcn_s_setprio(0);
#pragma unroll
    for (int m = 0; m < 4; ++m)
#pragma unroll
        for (int r = 0; r < 4; ++r)
            red[wave][m * 16 + rq + r][fr] = acc[m][r];
    __syncthreads();

    if (tid < 256) {
        const int bb = tid >> 2, j = tid & 3;
        const int col = hc0 + j;
        float G[4];
#pragma unroll
        for (int g = 0; g < 4; ++g) {
            const int f2 = g * 4 + j;
            float s = 0.f;
#pragma unroll
            for (int w16 = 0; w16 < 16; ++w16) s += red[w16][bb][f2];
            G[g] = s + xg[((size_t)t * 64 + bb) * 4096 + g * 1024 + col];
        }
        float ig = fast_sig(G[0]), fg = fast_sig(G[1]);
        float gv = fast_tanh(G[2]), og = fast_sig(G[3]);
        float cp = cbuf[bb * 1024 + col];
        float cn = fg * cp + ig * gv;
        cbuf[bb * 1024 + col] = cn;
        u16 hv = f2bu(og * fast_tanh(cn));
        h_nxt[(size_t)bb * 1024 + col] = hv;
        h_all[((size_t)bb * 32 + t) * 1024 + col] = hv;
    }
}

// ---------------------------------------------------------------------------
extern "C" void kernel_launch(void* const* d_in, const int* in_sizes, int n_in,
                              void* d_out, int out_size, void* d_ws, size_t ws_size,
                              hipStream_t stream)
{
    const float* img     = (const float*)d_in[0];
    const int*   tok     = (const int*)d_in[1];
    const float* embed   = (const float*)d_in[2];
    const float* W_head1 = (const float*)d_in[3];
    const float* W_ih    = (const float*)d_in[4];
    const float* W_hh    = (const float*)d_in[5];
    const float* b_ih    = (const float*)d_in[6];
    const float* b_hh    = (const float*)d_in[7];
    const float* W_head  = (const float*)d_in[8];
    const float* W_img   = (const float*)d_in[9];
    const float* W_hid   = (const float*)d_in[10];
    const float* w_score = (const float*)d_in[11];
    const float* W_h0    = (const float*)d_in[12];
    const float* b_h0    = (const float*)d_in[13];
    const float* W_c0    = (const float*)d_in[14];
    const float* b_c0    = (const float*)d_in[15];
    float* out = (float*)d_out;

    char* w = (char*)d_ws;
    size_t off = 0;
    auto alloc = [&](size_t bytes) { char* p = w + off; off += (bytes + 255) & ~(size_t)255; return p; };

    u16*   Wic      = (u16*)alloc(4096ULL * 2048 * 2);
    u16*   Whh_bf   = (u16*)alloc(4096ULL * 1024 * 2);
    u16*   Wpk      = (u16*)alloc(256ULL * 96 * 64 * 8 * 2);
    u16*   WhidT    = (u16*)alloc(256ULL * 1024 * 2);
    u16*   Whead_bf = (u16*)alloc(32000ULL * 1024 * 2);
    u16*   img_bf   = (u16*)alloc(64ULL * 196 * 2048 * 2);
    float* xg       = (float*)alloc(2048ULL * 4096 * 4);
    u16*   proj_bf  = (u16*)alloc(64ULL * 196 * 256 * 2);
    u16*   emb_bf   = (u16*)alloc(2048ULL * 512 * 2);
    u16*   xe       = (u16*)alloc(2048ULL * 512 * 2);
    float* gT       = (float*)alloc(2048ULL * 64 * 4);
    float* cbuf     = (float*)alloc(64ULL * 1024 * 4);
    u16*   hbuf     = (u16*)alloc(2ULL * 64 * 1024 * 2);
    u16*   ctx_bf   = (u16*)alloc(64ULL * 2048 * 2);
    u16*   h_all    = (u16*)alloc(2048ULL * 1024 * 2);
    float* bsum     = (float*)alloc(4096ULL * 4);
    (void)ws_size; (void)in_sizes; (void)n_in; (void)out_size;

    // ---- prologue (consolidated)
    prep_k<<<dim3(65552), dim3(256), 0, stream>>>(img, W_hh, W_hid, W_head, tok, embed,
                                                  b_ih, b_hh, img_bf, Whh_bf, WhidT,
                                                  Whead_bf, emb_bf, bsum);
    mean_k<<<dim3(256), dim3(256), 0, stream>>>(img_bf, gT);
    h0c0<<<dim3(256), dim3(256), 0, stream>>>(gT, W_h0, b_h0, W_c0, b_c0, cbuf, hbuf);

    // xe = emb @ Wa^T (Wa = W_head1[:, :512]); rows [t][b]
    gemm128<false, true, false, true, false><<<dim3(4, 16), dim3(256), 0, stream>>>(
        emb_bf, 512, W_head1, 2560, xe, 512, nullptr, 512);
    // xg = xe @ W_ih^T + (b_ih + b_hh); rows [t][b]
    gemm128<false, true, false, false, true><<<dim3(32, 16), dim3(256), 0, stream>>>(
        xe, 512, W_ih, 512, xg, 4096, bsum, 512);
    // Wic = W_ih @ W_head1[:, 512:]
    gemm128<true, true, true, true, false><<<dim3(16, 32), dim3(256), 0, stream>>>(
        W_ih, 512, W_head1 + 512, 2560, Wic, 2048, nullptr, 512);
    // proj_bf = img_bf @ W_img^T (bf16 out)
    gemm128<false, true, false, true, false><<<dim3(2, 98), dim3(256), 0, stream>>>(
        img_bf, 2048, W_img, 2048, proj_bf, 256, nullptr, 2048);
    // fragment-pack gates weights (needs Wic + Whh_bf)
    pack_w<<<dim3(24, 256), dim3(256), 0, stream>>>(Wic, Whh_bf, Wpk);

    // ---- recurrence: 2 kernels per step (R13 structure)
    for (int t = 0; t < 32; ++t) {
        u16* hb = hbuf + (size_t)(t & 1) * 65536;
        u16* hn = hbuf + (size_t)((t + 1) & 1) * 65536;
        attn_k<<<dim3(256), dim3(1024), 0, stream>>>(hb, WhidT, w_score, proj_bf, img_bf, ctx_bf);
        gates_k<<<dim3(256), dim3(1024), 0, stream>>>(ctx_bf, hb, Wpk, xg, cbuf, hn, h_all, t);
    }

    // ---- logits: out = h_all @ W_head^T (R13 counted-vmcnt pipeline)
    gemm_head<<<dim3(1000), dim3(1024), 0, stream>>>(h_all, Whead_bf, out);
}